// Round 1
// baseline (410.481 us; speedup 1.0000x reference)
//
#include <hip/hip_runtime.h>
#include <hip/hip_bf16.h>
#include <math.h>

typedef __hip_bfloat16 bf16;
typedef __attribute__((ext_vector_type(8))) __bf16 bf16x8;
typedef __attribute__((ext_vector_type(4))) float f32x4;

__device__ __forceinline__ void gload_lds16(const void* g, void* l) {
  __builtin_amdgcn_global_load_lds(
      (const __attribute__((address_space(1))) unsigned int*)g,
      (__attribute__((address_space(3))) unsigned int*)l, 16, 0, 0);
}

// ---------------- fp32 -> bf16 conversion, 8 elems/thread ----------------
__global__ void cvt_bf16(const float* __restrict__ in, bf16* __restrict__ out, int n) {
  int idx = (blockIdx.x * blockDim.x + threadIdx.x) * 8;
  if (idx >= n) return;
  float4 v0 = *(const float4*)(in + idx);
  float4 v1 = *(const float4*)(in + idx + 4);
  alignas(16) bf16 tmp[8];
  tmp[0] = __float2bfloat16(v0.x); tmp[1] = __float2bfloat16(v0.y);
  tmp[2] = __float2bfloat16(v0.z); tmp[3] = __float2bfloat16(v0.w);
  tmp[4] = __float2bfloat16(v1.x); tmp[5] = __float2bfloat16(v1.y);
  tmp[6] = __float2bfloat16(v1.z); tmp[7] = __float2bfloat16(v1.w);
  *(uint4*)(out + idx) = *(const uint4*)tmp;
}

__global__ void concat_bias(const float* __restrict__ a, const float* __restrict__ b,
                            const float* __restrict__ c, float* __restrict__ out) {
  int i = blockIdx.x * blockDim.x + threadIdx.x;
  if (i >= 3072) return;
  out[i] = (i < 1024) ? a[i] : (i < 2048 ? b[i - 1024] : c[i - 2048]);
}

// ---------------- GEMM: C[M,N] = A[M,K] @ Bw[N,K]^T + bias ----------------
// 128x128 tile, BK=32, 4 waves (2x2), each wave 64x64 = 4x4 fragments of 16x16.
template<int OUT_F32>
__global__ __launch_bounds__(256, 2) void gemm_bt(
    const bf16* __restrict__ A, const bf16* __restrict__ Bw,
    const float* __restrict__ bias, void* __restrict__ Cout,
    int N, int K)
{
  __shared__ bf16 lA[2][128 * 32];
  __shared__ bf16 lB[2][128 * 32];
  const int tid = threadIdx.x;
  const int wave = tid >> 6, lane = tid & 63;
  const int lhi = lane >> 4, llo = lane & 15;
  const int wr = wave >> 1, wc = wave & 1;
  const int row0 = blockIdx.x * 128, col0 = blockIdx.y * 128;

  auto stage = [&](int buf, int k0) {
#pragma unroll
    for (int it = 0; it < 2; ++it) {
      int i = it * 256 + tid;           // 512 chunks of 16B over the 8KB tile
      int r = i >> 2, kc = (i & 3) * 8; // row, k-elem offset
      gload_lds16(A  + (size_t)(row0 + r) * K + k0 + kc, &lA[buf][i * 8]);
      gload_lds16(Bw + (size_t)(col0 + r) * K + k0 + kc, &lB[buf][i * 8]);
    }
  };

  f32x4 acc[4][4] = {};
  const int KT = K >> 5;
  stage(0, 0);
  for (int kt = 0; kt < KT; ++kt) {
    __syncthreads();                       // drains vmcnt: buf[kt&1] ready
    if (kt + 1 < KT) stage((kt + 1) & 1, (kt + 1) << 5);
    const int buf = kt & 1;
    bf16x8 af[4], bfr[4];
#pragma unroll
    for (int m = 0; m < 4; ++m)
      af[m] = *(const bf16x8*)&lA[buf][(wr * 64 + m * 16 + llo) * 32 + lhi * 8];
#pragma unroll
    for (int n = 0; n < 4; ++n)
      bfr[n] = *(const bf16x8*)&lB[buf][(wc * 64 + n * 16 + llo) * 32 + lhi * 8];
#pragma unroll
    for (int m = 0; m < 4; ++m)
#pragma unroll
      for (int n = 0; n < 4; ++n)
        acc[m][n] = __builtin_amdgcn_mfma_f32_16x16x32_bf16(af[m], bfr[n], acc[m][n], 0, 0, 0);
  }

  // epilogue: C/D layout col=lane&15, row=(lane>>4)*4+j  [measured m89]
#pragma unroll
  for (int m = 0; m < 4; ++m)
#pragma unroll
    for (int n = 0; n < 4; ++n) {
      int col = col0 + wc * 64 + n * 16 + llo;
      float bv = bias[col];
#pragma unroll
      for (int j = 0; j < 4; ++j) {
        int row = row0 + wr * 64 + m * 16 + lhi * 4 + j;
        float v = acc[m][n][j] + bv;
        if (OUT_F32) ((float*)Cout)[(size_t)row * N + col] = v;
        else         ((bf16*)Cout)[(size_t)row * N + col] = __float2bfloat16(v);
      }
    }
}

// ---------------- V transpose: per (b,h) [S][64] -> [64][S] ----------------
__global__ __launch_bounds__(256) void transpose_v(
    const bf16* __restrict__ QKV, bf16* __restrict__ Vt)
{
  __shared__ bf16 t[64][72];
  const int st = blockIdx.x, h = blockIdx.y, b = blockIdx.z;
  const int tid = threadIdx.x;
#pragma unroll
  for (int it = 0; it < 2; ++it) {
    int i = it * 256 + tid;
    int r = i >> 3, c = (i & 7) * 8;
    bf16x8 v = *(const bf16x8*)&QKV[(size_t)(b * 2048 + st * 64 + r) * 3072 + 2048 + h * 64 + c];
#pragma unroll
    for (int j = 0; j < 8; ++j) t[r][c + j] = ((const bf16*)&v)[j];
  }
  __syncthreads();
#pragma unroll
  for (int it = 0; it < 2; ++it) {
    int i = it * 256 + tid;
    int d = i >> 3, c = (i & 7) * 8;
    alignas(16) bf16 tmp[8];
#pragma unroll
    for (int j = 0; j < 8; ++j) tmp[j] = t[c + j][d];
    *(uint4*)&Vt[(size_t)((b * 16 + h) * 64 + d) * 2048 + st * 64 + c] = *(const uint4*)tmp;
  }
}

// ---------------- causal flash attention ----------------
// block = (q-tile of 64, h, b); 4 waves x 16 q-rows; K/V tiles 64x64 double-buffered.
__global__ __launch_bounds__(256, 2) void attn(
    const bf16* __restrict__ QKV, const bf16* __restrict__ Vt,
    bf16* __restrict__ O)
{
  const int S = 2048, DM = 3072;
  const int qt = blockIdx.x, h = blockIdx.y, b = blockIdx.z;
  const int tid = threadIdx.x, wave = tid >> 6, lane = tid & 63;
  const int lhi = lane >> 4, llo = lane & 15;

  __shared__ bf16 lK[2][64 * 64];
  __shared__ bf16 lV[2][64 * 64];   // holds Vt tile: [d][s'] 64x64
  __shared__ bf16 lP[4][16 * 64];   // per-wave P staging

  const size_t rowb = (size_t)b * S;
  const int q0 = qt * 64;

  // Q fragments (A operand): row=lane&15, k contiguous 8 per (lane>>4)
  bf16x8 qf[2];
#pragma unroll
  for (int kk = 0; kk < 2; ++kk)
    qf[kk] = *(const bf16x8*)&QKV[(rowb + q0 + wave * 16 + llo) * DM + h * 64 + kk * 32 + lhi * 8];

  f32x4 o_acc[4] = {};
  float m_run[4], l_run[4];
#pragma unroll
  for (int j = 0; j < 4; ++j) { m_run[j] = -INFINITY; l_run[j] = 0.f; }

  const int nkt = qt + 1;  // causal: tiles 0..qt only
  auto stageKV = [&](int buf, int kt) {
#pragma unroll
    for (int it = 0; it < 2; ++it) {
      int i = it * 256 + tid;           // 512 chunks of 16B over 8KB
      int r = i >> 3, c = (i & 7) * 8;
      gload_lds16(&QKV[(rowb + (size_t)kt * 64 + r) * DM + 1024 + h * 64 + c], &lK[buf][i * 8]);
      gload_lds16(&Vt[(size_t)((b * 16 + h) * 64 + r) * S + kt * 64 + c],      &lV[buf][i * 8]);
    }
  };

  const float scl = 0.125f * 1.4426950408889634f;  // 1/sqrt(HD) * log2(e)

  stageKV(0, 0);
  for (int kt = 0; kt < nkt; ++kt) {
    __syncthreads();
    if (kt + 1 < nkt) stageKV((kt + 1) & 1, kt + 1);
    const int buf = kt & 1;

    // S = Q @ K^T : 16x64 per wave
    f32x4 s[4] = {};
#pragma unroll
    for (int n = 0; n < 4; ++n) {
      bf16x8 kf0 = *(const bf16x8*)&lK[buf][(n * 16 + llo) * 64 + lhi * 8];
      bf16x8 kf1 = *(const bf16x8*)&lK[buf][(n * 16 + llo) * 64 + 32 + lhi * 8];
      s[n] = __builtin_amdgcn_mfma_f32_16x16x32_bf16(qf[0], kf0, s[n], 0, 0, 0);
      s[n] = __builtin_amdgcn_mfma_f32_16x16x32_bf16(qf[1], kf1, s[n], 0, 0, 0);
    }

    const bool diag = (kt == nkt - 1);
#pragma unroll
    for (int j = 0; j < 4; ++j) {
      const int rowq = wave * 16 + lhi * 4 + j;  // q row within 64-block
      float mx = -INFINITY;
#pragma unroll
      for (int n = 0; n < 4; ++n) {
        if (diag && (n * 16 + llo) > rowq) s[n][j] = -INFINITY;
        mx = fmaxf(mx, s[n][j]);
      }
#pragma unroll
      for (int off = 1; off < 16; off <<= 1)
        mx = fmaxf(mx, __shfl_xor(mx, off));
      const float mnew = fmaxf(m_run[j], mx);
      const float corr = exp2f((m_run[j] - mnew) * scl);
      m_run[j] = mnew;
      float ps = 0.f;
#pragma unroll
      for (int n = 0; n < 4; ++n) {
        float p = exp2f((s[n][j] - mnew) * scl);
        s[n][j] = p;
        ps += p;
      }
#pragma unroll
      for (int off = 1; off < 16; off <<= 1)
        ps += __shfl_xor(ps, off);
      l_run[j] = l_run[j] * corr + ps;
#pragma unroll
      for (int n = 0; n < 4; ++n) o_acc[n][j] *= corr;
    }

    // P -> LDS (per-wave, C-layout indices), re-read as A fragments
#pragma unroll
    for (int n = 0; n < 4; ++n)
#pragma unroll
      for (int j = 0; j < 4; ++j)
        lP[wave][(lhi * 4 + j) * 64 + n * 16 + llo] = __float2bfloat16(s[n][j]);

#pragma unroll
    for (int kk = 0; kk < 2; ++kk) {
      bf16x8 pf = *(const bf16x8*)&lP[wave][llo * 64 + kk * 32 + lhi * 8];
#pragma unroll
      for (int n = 0; n < 4; ++n) {
        bf16x8 vf = *(const bf16x8*)&lV[buf][(n * 16 + llo) * 64 + kk * 32 + lhi * 8];
        o_acc[n] = __builtin_amdgcn_mfma_f32_16x16x32_bf16(pf, vf, o_acc[n], 0, 0, 0);
      }
    }
  }

  // normalize and write O as bf16 into [8192][1024]
#pragma unroll
  for (int n = 0; n < 4; ++n)
#pragma unroll
    for (int j = 0; j < 4; ++j) {
      float v = o_acc[n][j] / l_run[j];
      O[(rowb + q0 + wave * 16 + lhi * 4 + j) * 1024 + h * 64 + n * 16 + llo] = __float2bfloat16(v);
    }
}

extern "C" void kernel_launch(void* const* d_in, const int* in_sizes, int n_in,
                              void* d_out, int out_size, void* d_ws, size_t ws_size,
                              hipStream_t stream) {
  const float* x  = (const float*)d_in[0];
  const float* Wq = (const float*)d_in[1];
  const float* bq = (const float*)d_in[2];
  const float* Wk = (const float*)d_in[3];
  const float* bk = (const float*)d_in[4];
  const float* Wv = (const float*)d_in[5];
  const float* bv = (const float*)d_in[6];
  const float* Wo = (const float*)d_in[7];
  const float* bo = (const float*)d_in[8];

  const int Bb = 4, S = 2048, D = 1024;
  const int M = Bb * S;       // 8192
  const int N3 = 3 * D;       // 3072

  // workspace layout (bf16 elements)
  bf16* x16  = (bf16*)d_ws;                    // M*D      (reused as attn output)
  bf16* wqkv = x16 + (size_t)M * D;            // 3*D*D
  bf16* wo16 = wqkv + (size_t)3 * D * D;       // D*D
  bf16* qkv  = wo16 + (size_t)D * D;           // M*3D
  bf16* vt   = qkv + (size_t)M * N3;           // M*D
  float* b3  = (float*)(vt + (size_t)M * D);   // 3072 floats
  size_t needed = ((size_t)M * D * 3 + 4 * (size_t)D * D + (size_t)M * N3) * 2 + 3072 * 4;
  if (ws_size < needed) return;  // leaves d_out poisoned -> clear failure signal

  // conversions
  cvt_bf16<<<(M * D) / (8 * 256), 256, 0, stream>>>(x, x16, M * D);
  cvt_bf16<<<(D * D) / (8 * 256), 256, 0, stream>>>(Wq, wqkv, D * D);
  cvt_bf16<<<(D * D) / (8 * 256), 256, 0, stream>>>(Wk, wqkv + (size_t)D * D, D * D);
  cvt_bf16<<<(D * D) / (8 * 256), 256, 0, stream>>>(Wv, wqkv + (size_t)2 * D * D, D * D);
  cvt_bf16<<<(D * D) / (8 * 256), 256, 0, stream>>>(Wo, wo16, D * D);
  concat_bias<<<12, 256, 0, stream>>>(bq, bk, bv, b3);

  // fused QKV projection: [8192 x 3072] = x16 @ wqkv^T + b3
  gemm_bt<0><<<dim3(M / 128, N3 / 128), 256, 0, stream>>>(x16, wqkv, b3, qkv, N3, D);

  // V transpose per (b,h): [S][64] -> [64][S]
  transpose_v<<<dim3(S / 64, 16, Bb), 256, 0, stream>>>(qkv, vt);

  // causal attention -> attn_out (reuses x16)
  attn<<<dim3(S / 64, 16, Bb), 256, 0, stream>>>(qkv, vt, x16);

  // output projection, fp32 out
  gemm_bt<1><<<dim3(M / 128, D / 128), 256, 0, stream>>>(x16, wo16, bo, d_out, D, D);
}

// Round 2
// 248.447 us; speedup vs baseline: 1.6522x; 1.6522x over previous
//
#include <hip/hip_runtime.h>
#include <hip/hip_bf16.h>
#include <math.h>

typedef __hip_bfloat16 bf16;
typedef __attribute__((ext_vector_type(8))) __bf16 bf16x8;
typedef __attribute__((ext_vector_type(4))) float f32x4;

__device__ __forceinline__ void gload_lds16(const void* g, void* l) {
  __builtin_amdgcn_global_load_lds(
      (const __attribute__((address_space(1))) unsigned int*)g,
      (__attribute__((address_space(3))) unsigned int*)l, 16, 0, 0);
}

// ---------------- fp32 -> bf16 conversion, 8 elems/thread ----------------
__global__ void cvt_bf16(const float* __restrict__ in, bf16* __restrict__ out, int n) {
  int idx = (blockIdx.x * blockDim.x + threadIdx.x) * 8;
  if (idx >= n) return;
  float4 v0 = *(const float4*)(in + idx);
  float4 v1 = *(const float4*)(in + idx + 4);
  alignas(16) bf16 tmp[8];
  tmp[0] = __float2bfloat16(v0.x); tmp[1] = __float2bfloat16(v0.y);
  tmp[2] = __float2bfloat16(v0.z); tmp[3] = __float2bfloat16(v0.w);
  tmp[4] = __float2bfloat16(v1.x); tmp[5] = __float2bfloat16(v1.y);
  tmp[6] = __float2bfloat16(v1.z); tmp[7] = __float2bfloat16(v1.w);
  *(uint4*)(out + idx) = *(const uint4*)tmp;
}

__global__ void concat_bias(const float* __restrict__ a, const float* __restrict__ b,
                            const float* __restrict__ c, float* __restrict__ out) {
  int i = blockIdx.x * blockDim.x + threadIdx.x;
  if (i >= 3072) return;
  out[i] = (i < 1024) ? a[i] : (i < 2048 ? b[i - 1024] : c[i - 2048]);
}

// ---------------- GEMM: C[M,N] = A[M,K] @ Bw[N,K]^T + bias ----------------
template<int OUT_F32>
__global__ __launch_bounds__(256, 2) void gemm_bt(
    const bf16* __restrict__ A, const bf16* __restrict__ Bw,
    const float* __restrict__ bias, void* __restrict__ Cout,
    int N, int K)
{
  __shared__ bf16 lA[2][128 * 32];
  __shared__ bf16 lB[2][128 * 32];
  const int tid = threadIdx.x;
  const int wave = tid >> 6, lane = tid & 63;
  const int lhi = lane >> 4, llo = lane & 15;
  const int wr = wave >> 1, wc = wave & 1;
  const int row0 = blockIdx.x * 128, col0 = blockIdx.y * 128;

  auto stage = [&](int buf, int k0) {
#pragma unroll
    for (int it = 0; it < 2; ++it) {
      int i = it * 256 + tid;           // 512 chunks of 16B over the 8KB tile
      int r = i >> 2, kc = (i & 3) * 8; // row, k-elem offset
      gload_lds16(A  + (size_t)(row0 + r) * K + k0 + kc, &lA[buf][i * 8]);
      gload_lds16(Bw + (size_t)(col0 + r) * K + k0 + kc, &lB[buf][i * 8]);
    }
  };

  f32x4 acc[4][4] = {};
  const int KT = K >> 5;
  stage(0, 0);
  for (int kt = 0; kt < KT; ++kt) {
    __syncthreads();
    if (kt + 1 < KT) stage((kt + 1) & 1, (kt + 1) << 5);
    const int buf = kt & 1;
    bf16x8 af[4], bfr[4];
#pragma unroll
    for (int m = 0; m < 4; ++m)
      af[m] = *(const bf16x8*)&lA[buf][(wr * 64 + m * 16 + llo) * 32 + lhi * 8];
#pragma unroll
    for (int n = 0; n < 4; ++n)
      bfr[n] = *(const bf16x8*)&lB[buf][(wc * 64 + n * 16 + llo) * 32 + lhi * 8];
#pragma unroll
    for (int m = 0; m < 4; ++m)
#pragma unroll
      for (int n = 0; n < 4; ++n)
        acc[m][n] = __builtin_amdgcn_mfma_f32_16x16x32_bf16(af[m], bfr[n], acc[m][n], 0, 0, 0);
  }

#pragma unroll
  for (int m = 0; m < 4; ++m)
#pragma unroll
    for (int n = 0; n < 4; ++n) {
      int col = col0 + wc * 64 + n * 16 + llo;
      float bv = bias[col];
#pragma unroll
      for (int j = 0; j < 4; ++j) {
        int row = row0 + wr * 64 + m * 16 + lhi * 4 + j;
        float v = acc[m][n][j] + bv;
        if (OUT_F32) ((float*)Cout)[(size_t)row * N + col] = v;
        else         ((bf16*)Cout)[(size_t)row * N + col] = __float2bfloat16(v);
      }
    }
}

// ---------------- V transpose: per (b,h) [S][64] -> [64][S] ----------------
__global__ __launch_bounds__(256) void transpose_v(
    const bf16* __restrict__ QKV, bf16* __restrict__ Vt)
{
  __shared__ bf16 t[64][72];
  const int st = blockIdx.x, h = blockIdx.y, b = blockIdx.z;
  const int tid = threadIdx.x;
#pragma unroll
  for (int it = 0; it < 2; ++it) {
    int i = it * 256 + tid;
    int r = i >> 3, c = (i & 7) * 8;
    bf16x8 v = *(const bf16x8*)&QKV[(size_t)(b * 2048 + st * 64 + r) * 3072 + 2048 + h * 64 + c];
#pragma unroll
    for (int j = 0; j < 8; ++j) t[r][c + j] = ((const bf16*)&v)[j];
  }
  __syncthreads();
#pragma unroll
  for (int it = 0; it < 2; ++it) {
    int i = it * 256 + tid;
    int d = i >> 3, c = (i & 7) * 8;
    alignas(16) bf16 tmp[8];
#pragma unroll
    for (int j = 0; j < 8; ++j) tmp[j] = t[c + j][d];
    *(uint4*)&Vt[(size_t)((b * 16 + h) * 64 + d) * 2048 + st * 64 + c] = *(const uint4*)tmp;
  }
}

// ---------------- causal flash attention ----------------
// block = (q-tile PAIR {qt, 31-qt}, h, b) -> every block does exactly 33 KV
// tiles (perfect balance; 1024 blocks = 4/CU resident, no tail).
// 4 waves x 16 q-rows per q-tile; K/V 64x64 double-buffered, XOR-swizzled.
__global__ __launch_bounds__(256, 4) void attn(
    const bf16* __restrict__ QKV, const bf16* __restrict__ Vt,
    bf16* __restrict__ O)
{
  const int S = 2048, DM = 3072;
  const int qpair = blockIdx.x, h = blockIdx.y, b = blockIdx.z;
  const int tid = threadIdx.x, wave = tid >> 6, lane = tid & 63;
  const int lhi = lane >> 4, llo = lane & 15;

  __shared__ bf16 lK[2][64 * 64];   // K tile [kv][d], cols XOR-swizzled
  __shared__ bf16 lV[2][64 * 64];   // Vt tile [d][kv], cols XOR-swizzled
  __shared__ bf16 lP[4][16 * 64];   // per-wave P [q][kv], cols XOR-swizzled

  const size_t rowb = (size_t)b * S;
  const float scl = 0.125f * 1.4426950408889634f;  // 1/sqrt(HD) * log2(e)

  for (int job = 0; job < 2; ++job) {
    const int qt = job ? (31 - qpair) : qpair;
    const int q0 = qt * 64;
    const int nkt = qt + 1;

    // swizzle: LDS[row][c ^ ((row&7)<<3 elems)] holds data[row][c]
    auto stageKV = [&](int buf, int kt) {
#pragma unroll
      for (int it = 0; it < 2; ++it) {
        int i = it * 256 + tid;                    // 512 x 16B chunks
        int r = i >> 3;
        int ce = ((i & 7) * 8) ^ ((r & 7) << 3);   // pre-swizzled source col
        gload_lds16(&QKV[(rowb + (size_t)kt * 64 + r) * DM + 1024 + h * 64 + ce],
                    &lK[buf][i * 8]);
        gload_lds16(&Vt[((size_t)(b * 16 + h) * 64 + r) * S + kt * 64 + ce],
                    &lV[buf][i * 8]);
      }
    };

    // Q fragments (A operand), hoisted
    bf16x8 qf[2];
#pragma unroll
    for (int kk = 0; kk < 2; ++kk)
      qf[kk] = *(const bf16x8*)&QKV[(rowb + q0 + wave * 16 + llo) * DM + h * 64 + kk * 32 + lhi * 8];

    f32x4 o_acc[4] = {};
    float m_run[4], l_run[4];
#pragma unroll
    for (int j = 0; j < 4; ++j) { m_run[j] = -INFINITY; l_run[j] = 0.f; }

    __syncthreads();            // all waves done with previous job's LDS
    stageKV(0, 0);
    for (int kt = 0; kt < nkt; ++kt) {
      __syncthreads();          // staging of buf kt&1 complete
      if (kt + 1 < nkt) stageKV((kt + 1) & 1, kt + 1);
      const int buf = kt & 1;

      // S = Q @ K^T : 16x64 per wave
      f32x4 s[4] = {};
#pragma unroll
      for (int kk = 0; kk < 2; ++kk)
#pragma unroll
        for (int n = 0; n < 4; ++n) {
          const int kr = n * 16 + llo;
          bf16x8 kf = *(const bf16x8*)&lK[buf][kr * 64 + ((kk * 32 + lhi * 8) ^ ((kr & 7) << 3))];
          s[n] = __builtin_amdgcn_mfma_f32_16x16x32_bf16(qf[kk], kf, s[n], 0, 0, 0);
        }

      const bool diag = (kt == nkt - 1);
#pragma unroll
      for (int j = 0; j < 4; ++j) {
        const int rowq = wave * 16 + lhi * 4 + j;
        float mx = -INFINITY;
#pragma unroll
        for (int n = 0; n < 4; ++n) {
          if (diag && (n * 16 + llo) > rowq) s[n][j] = -INFINITY;
          mx = fmaxf(mx, s[n][j]);
        }
#pragma unroll
        for (int off = 1; off < 16; off <<= 1)
          mx = fmaxf(mx, __shfl_xor(mx, off));
        const float mnew = fmaxf(m_run[j], mx);
        const float corr = exp2f((m_run[j] - mnew) * scl);
        m_run[j] = mnew;
        float ps = 0.f;
#pragma unroll
        for (int n = 0; n < 4; ++n) {
          float p = exp2f((s[n][j] - mnew) * scl);
          s[n][j] = p;
          ps += p;
        }
#pragma unroll
        for (int off = 1; off < 16; off <<= 1)
          ps += __shfl_xor(ps, off);
        l_run[j] = l_run[j] * corr + ps;
#pragma unroll
        for (int n = 0; n < 4; ++n) o_acc[n][j] *= corr;
      }

      // P -> per-wave LDS (swizzled), re-read as A fragments
#pragma unroll
      for (int n = 0; n < 4; ++n)
#pragma unroll
        for (int j = 0; j < 4; ++j) {
          const int pr = lhi * 4 + j;
          lP[wave][pr * 64 + ((n * 16 + llo) ^ ((pr & 7) << 3))] = __float2bfloat16(s[n][j]);
        }

#pragma unroll
      for (int kk = 0; kk < 2; ++kk) {
        bf16x8 pf = *(const bf16x8*)&lP[wave][llo * 64 + ((kk * 32 + lhi * 8) ^ ((llo & 7) << 3))];
#pragma unroll
        for (int n = 0; n < 4; ++n) {
          const int vr = n * 16 + llo;
          bf16x8 vf = *(const bf16x8*)&lV[buf][vr * 64 + ((kk * 32 + lhi * 8) ^ ((vr & 7) << 3))];
          o_acc[n] = __builtin_amdgcn_mfma_f32_16x16x32_bf16(pf, vf, o_acc[n], 0, 0, 0);
        }
      }
    }

    // normalize and write O as bf16 into [8192][1024]
#pragma unroll
    for (int n = 0; n < 4; ++n)
#pragma unroll
      for (int j = 0; j < 4; ++j) {
        float v = o_acc[n][j] / l_run[j];
        O[(rowb + q0 + wave * 16 + lhi * 4 + j) * 1024 + h * 64 + n * 16 + llo] = __float2bfloat16(v);
      }
  }
}

extern "C" void kernel_launch(void* const* d_in, const int* in_sizes, int n_in,
                              void* d_out, int out_size, void* d_ws, size_t ws_size,
                              hipStream_t stream) {
  const float* x  = (const float*)d_in[0];
  const float* Wq = (const float*)d_in[1];
  const float* bq = (const float*)d_in[2];
  const float* Wk = (const float*)d_in[3];
  const float* bk = (const float*)d_in[4];
  const float* Wv = (const float*)d_in[5];
  const float* bv = (const float*)d_in[6];
  const float* Wo = (const float*)d_in[7];
  const float* bo = (const float*)d_in[8];

  const int Bb = 4, S = 2048, D = 1024;
  const int M = Bb * S;       // 8192
  const int N3 = 3 * D;       // 3072

  bf16* x16  = (bf16*)d_ws;                    // M*D (reused as attn output)
  bf16* wqkv = x16 + (size_t)M * D;            // 3*D*D
  bf16* wo16 = wqkv + (size_t)3 * D * D;       // D*D
  bf16* qkv  = wo16 + (size_t)D * D;           // M*3D
  bf16* vt   = qkv + (size_t)M * N3;           // M*D
  float* b3  = (float*)(vt + (size_t)M * D);   // 3072 floats
  size_t needed = ((size_t)M * D * 3 + 4 * (size_t)D * D + (size_t)M * N3) * 2 + 3072 * 4;
  if (ws_size < needed) return;

  cvt_bf16<<<(M * D) / (8 * 256), 256, 0, stream>>>(x, x16, M * D);
  cvt_bf16<<<(D * D) / (8 * 256), 256, 0, stream>>>(Wq, wqkv, D * D);
  cvt_bf16<<<(D * D) / (8 * 256), 256, 0, stream>>>(Wk, wqkv + (size_t)D * D, D * D);
  cvt_bf16<<<(D * D) / (8 * 256), 256, 0, stream>>>(Wv, wqkv + (size_t)2 * D * D, D * D);
  cvt_bf16<<<(D * D) / (8 * 256), 256, 0, stream>>>(Wo, wo16, D * D);
  concat_bias<<<12, 256, 0, stream>>>(bq, bk, bv, b3);

  gemm_bt<0><<<dim3(M / 128, N3 / 128), 256, 0, stream>>>(x16, wqkv, b3, qkv, N3, D);
  transpose_v<<<dim3(S / 64, 16, Bb), 256, 0, stream>>>(qkv, vt);
  attn<<<dim3(S / 128, 16, Bb), 256, 0, stream>>>(qkv, vt, x16);
  gemm_bt<1><<<dim3(M / 128, D / 128), 256, 0, stream>>>(x16, wo16, bo, d_out, D, D);
}

// Round 3
// 212.795 us; speedup vs baseline: 1.9290x; 1.1675x over previous
//
#include <hip/hip_runtime.h>
#include <hip/hip_bf16.h>
#include <math.h>

typedef __hip_bfloat16 bf16;
typedef __attribute__((ext_vector_type(8))) __bf16 bf16x8;
typedef __attribute__((ext_vector_type(4))) float f32x4;

__device__ __forceinline__ void gload_lds16(const void* g, void* l) {
  __builtin_amdgcn_global_load_lds(
      (const __attribute__((address_space(1))) unsigned int*)g,
      (__attribute__((address_space(3))) unsigned int*)l, 16, 0, 0);
}

// ---------------- fp32 -> bf16 conversion, 8 elems/thread ----------------
__global__ void cvt_bf16(const float* __restrict__ in, bf16* __restrict__ out, int n) {
  int idx = (blockIdx.x * blockDim.x + threadIdx.x) * 8;
  if (idx >= n) return;
  float4 v0 = *(const float4*)(in + idx);
  float4 v1 = *(const float4*)(in + idx + 4);
  alignas(16) bf16 tmp[8];
  tmp[0] = __float2bfloat16(v0.x); tmp[1] = __float2bfloat16(v0.y);
  tmp[2] = __float2bfloat16(v0.z); tmp[3] = __float2bfloat16(v0.w);
  tmp[4] = __float2bfloat16(v1.x); tmp[5] = __float2bfloat16(v1.y);
  tmp[6] = __float2bfloat16(v1.z); tmp[7] = __float2bfloat16(v1.w);
  *(uint4*)(out + idx) = *(const uint4*)tmp;
}

__global__ void concat_bias(const float* __restrict__ a, const float* __restrict__ b,
                            const float* __restrict__ c, float* __restrict__ out) {
  int i = blockIdx.x * blockDim.x + threadIdx.x;
  if (i >= 3072) return;
  out[i] = (i < 1024) ? a[i] : (i < 2048 ? b[i - 1024] : c[i - 2048]);
}

// ---------------- GEMM: C[M,N] = A[M,K] @ Bw[N,K]^T + bias ----------------
template<int OUT_F32>
__global__ __launch_bounds__(256, 2) void gemm_bt(
    const bf16* __restrict__ A, const bf16* __restrict__ Bw,
    const float* __restrict__ bias, void* __restrict__ Cout,
    int N, int K)
{
  __shared__ bf16 lA[2][128 * 32];
  __shared__ bf16 lB[2][128 * 32];
  const int tid = threadIdx.x;
  const int wave = tid >> 6, lane = tid & 63;
  const int lhi = lane >> 4, llo = lane & 15;
  const int wr = wave >> 1, wc = wave & 1;
  const int row0 = blockIdx.x * 128, col0 = blockIdx.y * 128;

  auto stage = [&](int buf, int k0) {
#pragma unroll
    for (int it = 0; it < 2; ++it) {
      int i = it * 256 + tid;
      int r = i >> 2, kc = (i & 3) * 8;
      gload_lds16(A  + (size_t)(row0 + r) * K + k0 + kc, &lA[buf][i * 8]);
      gload_lds16(Bw + (size_t)(col0 + r) * K + k0 + kc, &lB[buf][i * 8]);
    }
  };

  f32x4 acc[4][4] = {};
  const int KT = K >> 5;
  stage(0, 0);
  for (int kt = 0; kt < KT; ++kt) {
    __syncthreads();
    if (kt + 1 < KT) stage((kt + 1) & 1, (kt + 1) << 5);
    const int buf = kt & 1;
    bf16x8 af[4], bfr[4];
#pragma unroll
    for (int m = 0; m < 4; ++m)
      af[m] = *(const bf16x8*)&lA[buf][(wr * 64 + m * 16 + llo) * 32 + lhi * 8];
#pragma unroll
    for (int n = 0; n < 4; ++n)
      bfr[n] = *(const bf16x8*)&lB[buf][(wc * 64 + n * 16 + llo) * 32 + lhi * 8];
#pragma unroll
    for (int m = 0; m < 4; ++m)
#pragma unroll
      for (int n = 0; n < 4; ++n)
        acc[m][n] = __builtin_amdgcn_mfma_f32_16x16x32_bf16(af[m], bfr[n], acc[m][n], 0, 0, 0);
  }

#pragma unroll
  for (int m = 0; m < 4; ++m)
#pragma unroll
    for (int n = 0; n < 4; ++n) {
      int col = col0 + wc * 64 + n * 16 + llo;
      float bv = bias[col];
#pragma unroll
      for (int j = 0; j < 4; ++j) {
        int row = row0 + wr * 64 + m * 16 + lhi * 4 + j;
        float v = acc[m][n][j] + bv;
        if (OUT_F32) ((float*)Cout)[(size_t)row * N + col] = v;
        else         ((bf16*)Cout)[(size_t)row * N + col] = __float2bfloat16(v);
      }
    }
}

// ---------------- V transpose: per (b,h) [S][64] -> [64][S] ----------------
__global__ __launch_bounds__(256) void transpose_v(
    const bf16* __restrict__ QKV, bf16* __restrict__ Vt)
{
  __shared__ bf16 t[64][72];
  const int st = blockIdx.x, h = blockIdx.y, b = blockIdx.z;
  const int tid = threadIdx.x;
#pragma unroll
  for (int it = 0; it < 2; ++it) {
    int i = it * 256 + tid;
    int r = i >> 3, c = (i & 7) * 8;
    bf16x8 v = *(const bf16x8*)&QKV[(size_t)(b * 2048 + st * 64 + r) * 3072 + 2048 + h * 64 + c];
#pragma unroll
    for (int j = 0; j < 8; ++j) t[r][c + j] = ((const bf16*)&v)[j];
  }
  __syncthreads();
#pragma unroll
  for (int it = 0; it < 2; ++it) {
    int i = it * 256 + tid;
    int d = i >> 3, c = (i & 7) * 8;
    alignas(16) bf16 tmp[8];
#pragma unroll
    for (int j = 0; j < 8; ++j) tmp[j] = t[c + j][d];
    *(uint4*)&Vt[(size_t)((b * 16 + h) * 64 + d) * 2048 + st * 64 + c] = *(const uint4*)tmp;
  }
}

// ---------------- causal flash attention (swapped-operand form) ----------------
// block = (q-tile PAIR {qt, 31-qt}, h, b): exactly 33 KV tiles per block.
// Swapped MFMAs: S^T = mfma(K,Q) and O^T = mfma(V^T,P) so that q = lane&15 in
// both C-layouts -> softmax reduction is in-lane + 2 shfl; m/l are per-lane
// scalars; no cross-lane broadcast for the rescale.
__global__ __launch_bounds__(256, 4) void attn(
    const bf16* __restrict__ QKV, const bf16* __restrict__ Vt,
    bf16* __restrict__ O)
{
  const int S = 2048, DM = 3072;
  const int qpair = blockIdx.x, h = blockIdx.y, b = blockIdx.z;
  const int tid = threadIdx.x, wave = tid >> 6, lane = tid & 63;
  const int lhi = lane >> 4, llo = lane & 15;

  __shared__ bf16 lK[2][64 * 64];   // K tile [kv][d], 8-elem col groups XOR-swizzled by row
  __shared__ bf16 lV[2][64 * 64];   // Vt tile [d][kv], same swizzle
  __shared__ bf16 lP[4][16 * 64];   // per-wave P [q][kv], 4-elem groups swizzled by q

  const size_t rowb = (size_t)b * S;
  const float scl = 0.125f * 1.4426950408889634f;  // 1/sqrt(HD) * log2(e)

  for (int job = 0; job < 2; ++job) {
    const int qt = job ? (31 - qpair) : qpair;
    const int q0 = qt * 64;
    const int nkt = qt + 1;

    auto stageKV = [&](int buf, int kt) {
#pragma unroll
      for (int it = 0; it < 2; ++it) {
        int i = it * 256 + tid;
        int r = i >> 3;
        int ce = ((i & 7) * 8) ^ ((r & 7) << 3);   // pre-swizzled source col
        gload_lds16(&QKV[(rowb + (size_t)kt * 64 + r) * DM + 1024 + h * 64 + ce],
                    &lK[buf][i * 8]);
        gload_lds16(&Vt[((size_t)(b * 16 + h) * 64 + r) * S + kt * 64 + ce],
                    &lV[buf][i * 8]);
      }
    };

    // Q fragment (B operand): col=lane&15 = q-row, k = kk*32 + lhi*8
    bf16x8 qf[2];
#pragma unroll
    for (int kk = 0; kk < 2; ++kk)
      qf[kk] = *(const bf16x8*)&QKV[(rowb + q0 + wave * 16 + llo) * DM + h * 64 + kk * 32 + lhi * 8];

    f32x4 o_acc[4] = {};          // o_acc[n][j] = O^T[d = n*16+lhi*4+j][q = llo]
    float m_run = -INFINITY, l_run = 0.f;

    __syncthreads();              // previous job done with LDS
    stageKV(0, 0);
    for (int kt = 0; kt < nkt; ++kt) {
      __syncthreads();            // buf kt&1 staged
      if (kt + 1 < nkt) stageKV((kt + 1) & 1, kt + 1);
      const int buf = kt & 1;

      // S^T = mfma(K, Q): s[n][j] = S[kv = n*16+lhi*4+j][q = llo]
      f32x4 s[4] = {};
#pragma unroll
      for (int kk = 0; kk < 2; ++kk)
#pragma unroll
        for (int n = 0; n < 4; ++n) {
          const int kr = n * 16 + llo;
          bf16x8 kf = *(const bf16x8*)&lK[buf][kr * 64 + ((kk * 32 + lhi * 8) ^ ((kr & 7) << 3))];
          s[n] = __builtin_amdgcn_mfma_f32_16x16x32_bf16(kf, qf[kk], s[n], 0, 0, 0);
        }

      // causal mask on diagonal tile: kv_local > q_local
      if (kt == nkt - 1) {
        const int ql = wave * 16 + llo;
#pragma unroll
        for (int n = 0; n < 4; ++n)
#pragma unroll
          for (int j = 0; j < 4; ++j)
            if (n * 16 + lhi * 4 + j > ql) s[n][j] = -INFINITY;
      }

      // online softmax: per-lane row (q = llo), 16 kv values in-lane
      float mx = -INFINITY;
#pragma unroll
      for (int n = 0; n < 4; ++n)
#pragma unroll
        for (int j = 0; j < 4; ++j) mx = fmaxf(mx, s[n][j]);
      mx = fmaxf(mx, __shfl_xor(mx, 16));
      mx = fmaxf(mx, __shfl_xor(mx, 32));
      const float mnew = fmaxf(m_run, mx);
      const float corr = exp2f((m_run - mnew) * scl);
      float ps = 0.f;
#pragma unroll
      for (int n = 0; n < 4; ++n)
#pragma unroll
        for (int j = 0; j < 4; ++j) {
          float p = exp2f((s[n][j] - mnew) * scl);
          s[n][j] = p;
          ps += p;
        }
      ps += __shfl_xor(ps, 16);
      ps += __shfl_xor(ps, 32);
      l_run = l_run * corr + ps;
      m_run = mnew;
#pragma unroll
      for (int n = 0; n < 4; ++n)
#pragma unroll
        for (int j = 0; j < 4; ++j) o_acc[n][j] *= corr;

      // P -> lP[q][kv]: lane writes 4 contiguous kv (j=0..3) per n as one b64.
      // 4-elem group index g = n*4+lhi, swizzle g ^= (llo&7)<<1 (even: preserves
      // 16B read order), conflict-free both sides.
#pragma unroll
      for (int n = 0; n < 4; ++n) {
        alignas(8) bf16 tmp[4];
#pragma unroll
        for (int j = 0; j < 4; ++j) tmp[j] = __float2bfloat16(s[n][j]);
        const int g = (n * 4 + lhi) ^ ((llo & 7) << 1);
        *(uint2*)&lP[wave][llo * 64 + g * 4] = *(const uint2*)tmp;
      }

      // O^T += mfma(V^T, P): pf is B operand (col = q = llo, k = kv)
#pragma unroll
      for (int kk = 0; kk < 2; ++kk) {
        const int g0 = (kk * 8 + lhi * 2) ^ ((llo & 7) << 1);
        bf16x8 pf = *(const bf16x8*)&lP[wave][llo * 64 + g0 * 4];
#pragma unroll
        for (int n = 0; n < 4; ++n) {
          const int vr = n * 16 + llo;
          bf16x8 vf = *(const bf16x8*)&lV[buf][vr * 64 + ((kk * 32 + lhi * 8) ^ ((vr & 7) << 3))];
          o_acc[n] = __builtin_amdgcn_mfma_f32_16x16x32_bf16(vf, pf, o_acc[n], 0, 0, 0);
        }
      }
    }

    // write O: lane owns q = llo, d = n*16 + lhi*4 + j (j contiguous -> b64)
    const float inv = 1.0f / l_run;
    const size_t orow = (rowb + q0 + wave * 16 + llo) * 1024 + h * 64;
#pragma unroll
    for (int n = 0; n < 4; ++n) {
      alignas(8) bf16 tmp[4];
#pragma unroll
      for (int j = 0; j < 4; ++j) tmp[j] = __float2bfloat16(o_acc[n][j] * inv);
      *(uint2*)&O[orow + n * 16 + lhi * 4] = *(const uint2*)tmp;
    }
  }
}

extern "C" void kernel_launch(void* const* d_in, const int* in_sizes, int n_in,
                              void* d_out, int out_size, void* d_ws, size_t ws_size,
                              hipStream_t stream) {
  const float* x  = (const float*)d_in[0];
  const float* Wq = (const float*)d_in[1];
  const float* bq = (const float*)d_in[2];
  const float* Wk = (const float*)d_in[3];
  const float* bk = (const float*)d_in[4];
  const float* Wv = (const float*)d_in[5];
  const float* bv = (const float*)d_in[6];
  const float* Wo = (const float*)d_in[7];
  const float* bo = (const float*)d_in[8];

  const int Bb = 4, S = 2048, D = 1024;
  const int M = Bb * S;       // 8192
  const int N3 = 3 * D;       // 3072

  bf16* x16  = (bf16*)d_ws;                    // M*D (reused as attn output)
  bf16* wqkv = x16 + (size_t)M * D;            // 3*D*D
  bf16* wo16 = wqkv + (size_t)3 * D * D;       // D*D
  bf16* qkv  = wo16 + (size_t)D * D;           // M*3D
  bf16* vt   = qkv + (size_t)M * N3;           // M*D
  float* b3  = (float*)(vt + (size_t)M * D);   // 3072 floats
  size_t needed = ((size_t)M * D * 3 + 4 * (size_t)D * D + (size_t)M * N3) * 2 + 3072 * 4;
  if (ws_size < needed) return;

  cvt_bf16<<<(M * D) / (8 * 256), 256, 0, stream>>>(x, x16, M * D);
  cvt_bf16<<<(D * D) / (8 * 256), 256, 0, stream>>>(Wq, wqkv, D * D);
  cvt_bf16<<<(D * D) / (8 * 256), 256, 0, stream>>>(Wk, wqkv + (size_t)D * D, D * D);
  cvt_bf16<<<(D * D) / (8 * 256), 256, 0, stream>>>(Wv, wqkv + (size_t)2 * D * D, D * D);
  cvt_bf16<<<(D * D) / (8 * 256), 256, 0, stream>>>(Wo, wo16, D * D);
  concat_bias<<<12, 256, 0, stream>>>(bq, bk, bv, b3);

  gemm_bt<0><<<dim3(M / 128, N3 / 128), 256, 0, stream>>>(x16, wqkv, b3, qkv, N3, D);
  transpose_v<<<dim3(S / 64, 16, Bb), 256, 0, stream>>>(qkv, vt);
  attn<<<dim3(S / 128, 16, Bb), 256, 0, stream>>>(qkv, vt, x16);
  gemm_bt<1><<<dim3(M / 128, D / 128), 256, 0, stream>>>(x16, wo16, bo, d_out, D, D);
}